// Round 1
// 88.826 us; speedup vs baseline: 1.1355x; 1.1355x over previous
//
#include <hip/hip_runtime.h>

#define BATCH 65536
#define NSPL  64
#define CDIM  64
#define TDIM  68          // CDIM + DEGREE + 1
#define QI    67          // degree-0 intervals
#define RTN   67          // region-table entries per spline

#define TCOLS 16          // splines per block: full 64B line per row
#define TROWS 128         // rows per block (2 rows/lane/column)
#define NTHR  256
#define PITCH 129         // 129 % 32 == 1: compute-phase stride-1 reads free
#define KPAD  128         // sorted knots padded to 128 (+INF tail) for 7-step search

// ============================================================================
// Sorted-region formulation (R8, proven): S(x) is piecewise-cubic with
// breakpoints at the sorted knot values; region index m = #{j: x >= t_j} over
// the ORIGINAL knots (order-independent count); prep sums active Q_i per
// region (fp64) -> RT[spline][m-1] float4; m=0/68 -> 0.
// R11: the count is order-independent over the knot MULTISET, and prep
// already rank-sorts the knots -> replace the 68-iteration linear count
// (272 VALU + 68 s_load per wave-column, the dominant kernel-side cost) with
// a 7-step branchless binary search over sorted knots staged in LDS
// (srt padded to 128 with +INF; n = sum of accepted power-of-2 steps).
// Identical predicate (t_j <= x), identical count, ~5x fewer count-phase ops.
// RT gather stays on the global/VMEM path (R10, proven vs LDS gather).
// ============================================================================

__global__ __launch_bounds__(128) void prep(const float* __restrict__ T,
                                            const float* __restrict__ C,
                                            float4* __restrict__ RT,
                                            float* __restrict__ SRT) {
    __shared__ double  td[TDIM];
    __shared__ double  cd[CDIM];
    __shared__ double  R1[QI], R2[TDIM - 2], R3[TDIM - 3];
    __shared__ double4 Qd[QI];
    __shared__ float   tf[TDIM];
    __shared__ float   srt[TDIM];

    const int s = blockIdx.x;
    const int t = threadIdx.x;

    if (t < TDIM) { float v = T[s * TDIM + t]; tf[t] = v; td[t] = (double)v; }
    if (t >= 64 && t < 64 + CDIM) cd[t - 64] = (double)C[s * CDIM + t - 64];
    __syncthreads();

    // Safe reciprocals (0/0 := 0; fp64 diff is 0 iff fp32 values equal).
    if (t < TDIM - 1) { double d = td[t + 1] - td[t]; R1[t] = (d == 0.0) ? 0.0 : 1.0 / d; }
    if (t < TDIM - 2) { double d = td[t + 2] - td[t]; R2[t] = (d == 0.0) ? 0.0 : 1.0 / d; }
    if (t < TDIM - 3) { double d = td[t + 3] - td[t]; R3[t] = (d == 0.0) ? 0.0 : 1.0 / d; }
    // Rank-sort the 68 knots (ties broken by index -> deterministic).
    if (t < TDIM) {
        float v = tf[t];
        int r = 0;
        for (int k = 0; k < TDIM; ++k)
            r += (tf[k] < v) || (tf[k] == v && k < t);
        srt[r] = v;
    }
    __syncthreads();

    // Export sorted knots, padded to 128 with +INF (search pad: INF <= x is
    // always false for finite x, so the count is unaffected).
    {
        float v = (t < TDIM) ? srt[t] : __builtin_huge_valf();
        SRT[s * KPAD + t] = v;
    }

    // Expand Q_i: cubic for interval i, sum over <=8 Cox-de Boor lattice paths.
    if (t < QI) {
        const int i = t;
        double q0 = 0, q1 = 0, q2 = 0, q3 = 0;
        for (int j = i - 3; j <= i; ++j) {
            if (j < 0 || j > CDIM - 1) continue;
            double cj = cd[j];
            for (int b2 = 0; b2 < 2; ++b2) {
                int m2 = j + b2;
                double D3 = R3[j + b2];
                double p3 = b2 ? -D3 : D3;
                double r3 = b2 ? D3 * td[j + 4] : -D3 * td[j];
                for (int b1 = 0; b1 < 2; ++b1) {
                    int m1 = m2 + b1;
                    double D2 = R2[m2 + b1];
                    double p2 = b1 ? -D2 : D2;
                    double r2 = b1 ? D2 * td[m2 + 3] : -D2 * td[m2];
                    for (int b0 = 0; b0 < 2; ++b0) {
                        if (m1 + b0 != i) continue;   // path must end at interval i
                        double D1 = R1[m1 + b0];
                        double p1 = b0 ? -D1 : D1;
                        double r1 = b0 ? D1 * td[m1 + 2] : -D1 * td[m1];
                        double a2 = p3 * p2, a1 = p3 * r2 + r3 * p2, a0 = r3 * r2;
                        q3 += cj * (a2 * p1);
                        q2 += cj * (a2 * r1 + a1 * p1);
                        q1 += cj * (a1 * r1 + a0 * p1);
                        q0 += cj * (a0 * r1);
                    }
                }
            }
        }
        double4 q; q.x = q0; q.y = q1; q.z = q2; q.w = q3;
        Qd[i] = q;
    }
    __syncthreads();

    // Region sums: for m = t in 1..67, x* = srt[m-1]; active i <=> same fp32
    // predicates as the reference. Coefficient-wise fp64 sum -> fp32 cubic.
    if (t >= 1 && t <= RTN) {
        const float xs = srt[t - 1];
        double a0 = 0, a1 = 0, a2 = 0, a3 = 0;
        for (int i = 0; i < QI; ++i) {
            if (tf[i] <= xs && xs < tf[i + 1]) {
                double4 q = Qd[i];
                a0 += q.x; a1 += q.y; a2 += q.z; a3 += q.w;
            }
        }
        float4 v; v.x = (float)a0; v.y = (float)a1; v.z = (float)a2; v.w = (float)a3;
        RT[s * RTN + (t - 1)] = v;
    }
}

__global__ __launch_bounds__(NTHR) void bspline_main(const float* __restrict__ X,
                                                     const float4* __restrict__ RT,
                                                     const float* __restrict__ SRT,
                                                     float* __restrict__ O) {
    __shared__ float xl[TCOLS * PITCH];   // 8,256 B: x tile [col][row]; reused for out
    __shared__ float ks[TCOLS * KPAD];    // 8,192 B: sorted+padded knots per column

    const int tid  = threadIdx.x;
    const int lane = tid & 63;
    const int w    = tid >> 6;
    const int r0   = blockIdx.x * TROWS;
    const int s0   = blockIdx.y * TCOLS;

    // Stage sorted knots: 16 splines x 128 floats = 512 float4, 2 per thread.
    // Coalesced 1KB/wave-instr loads; ds_write_b128 lane i -> banks 4i..4i+3
    // mod 32: every 8 lanes cover all 32 banks exactly once -> conflict-free.
    {
        const float4* src = (const float4*)(SRT + s0 * KPAD);
        float4* dst = (float4*)ks;
        dst[tid]        = src[tid];
        dst[tid + NTHR] = src[tid + NTHR];
    }
    // Stage X tile as float4 (4 rows of 16 splines per wave-instr = 1KB
    // coalesced); scatter-transpose into LDS: bank (4q+k+r)%32, <=4-way.
    #pragma unroll
    for (int it = 0; it < 2; ++it) {
        int e = tid + it * NTHR;
        int r = e >> 2, q = e & 3;
        float4 v = *(const float4*)(X + (r0 + r) * NSPL + s0 + q * 4);
        xl[(q * 4 + 0) * PITCH + r] = v.x;
        xl[(q * 4 + 1) * PITCH + r] = v.y;
        xl[(q * 4 + 2) * PITCH + r] = v.z;
        xl[(q * 4 + 3) * PITCH + r] = v.w;
    }
    __syncthreads();

    // Wave w owns columns 4w..4w+3 exclusively; 2 rows per lane per column.
    #pragma unroll 1
    for (int cc = 0; cc < 4; ++cc) {
        const int c  = w * 4 + cc;
        const int sp = __builtin_amdgcn_readfirstlane(s0 + c);
        const float* kc = ks + c * KPAD;

        float* xc = xl + c * PITCH + lane;
        const float x0 = xc[0];                   // stride-1: conflict-free
        const float x1 = xc[64];

        // 7-step branchless upper-bound over the sorted 68 knots (padded to
        // 128 with +INF): n = #{k: srt[k] <= x} = #{j: x >= t_j} (multiset
        // equality -> identical to the linear count over original knots).
        // Early steps broadcast (same addr across lanes); late steps spread
        // over 68 words / 32 banks -> <=3-way, effectively free.
        unsigned n0 = 0, n1 = 0;
        #pragma unroll
        for (int st = 64; st >= 1; st >>= 1) {
            float v0 = kc[n0 + st - 1];
            float v1 = kc[n1 + st - 1];
            n0 = (v0 <= x0) ? n0 + st : n0;
            n1 = (v1 <= x1) ? n1 + st : n1;
        }
        // Region m = n; table entry m-1 for m in [1,67]; m=0/68 -> 0.
        unsigned i0 = n0 - 1u; i0 = (i0 > 66u) ? 66u : i0;   // wrap(n=0)->66 too
        unsigned i1 = n1 - 1u; i1 = (i1 > 66u) ? 66u : i1;
        // Gather straight from global: ~1KB/spline -> L1/L2-resident, VMEM
        // path, zero LDS-pipe cost (R10, proven vs LDS gather).
        const float4* rts = RT + sp * RTN;
        float4 p0 = rts[i0];
        float4 p1 = rts[i1];
        float y0 = fmaf(fmaf(fmaf(p0.w, x0, p0.z), x0, p0.y), x0, p0.x);
        float y1 = fmaf(fmaf(fmaf(p1.w, x1, p1.z), x1, p1.y), x1, p1.x);
        y0 = (n0 - 1u < 67u) ? y0 : 0.f;          // m=0 or m=68 -> outside knots
        y1 = (n1 - 1u < 67u) ? y1 : 0.f;
        // In-place write-back: column c touched only by wave w; x reads done.
        xc[0]  = y0;
        xc[64] = y1;
    }
    __syncthreads();

    // Write out: gather-transpose from LDS, full 1KB float4 stores per wave.
    #pragma unroll
    for (int it = 0; it < 2; ++it) {
        int e = tid + it * NTHR;
        int r = e >> 2, q = e & 3;
        float4 v;
        v.x = xl[(q * 4 + 0) * PITCH + r];
        v.y = xl[(q * 4 + 1) * PITCH + r];
        v.z = xl[(q * 4 + 2) * PITCH + r];
        v.w = xl[(q * 4 + 3) * PITCH + r];
        *(float4*)(O + (r0 + r) * NSPL + s0 + q * 4) = v;
    }
}

extern "C" void kernel_launch(void* const* d_in, const int* in_sizes, int n_in,
                              void* d_out, int out_size, void* d_ws, size_t ws_size,
                              hipStream_t stream) {
    const float* X = (const float*)d_in[0];  // [65536, 64]
    const float* T = (const float*)d_in[1];  // [64, 68]
    const float* C = (const float*)d_in[2];  // [64, 64]
    float* O = (float*)d_out;                // [65536, 64]
    float4* RT = (float4*)d_ws;              // 64*67 float4 = 68,608 B
    float* SRT = (float*)((char*)d_ws + NSPL * RTN * sizeof(float4));  // 64*128 f32 = 32 KB

    prep<<<NSPL, 128, 0, stream>>>(T, C, RT, SRT);
    dim3 grid(BATCH / TROWS, NSPL / TCOLS);  // (512, 4) = 2048 blocks, 8/CU resident
    bspline_main<<<grid, NTHR, 0, stream>>>(X, RT, SRT, O);
}

// Round 2
// 88.668 us; speedup vs baseline: 1.1376x; 1.0018x over previous
//
#include <hip/hip_runtime.h>

#define BATCH 65536
#define NSPL  64
#define CDIM  64
#define TDIM  68          // CDIM + DEGREE + 1
#define QI    67          // degree-0 intervals
#define RTN   67          // region-table entries per spline

#define TCOLS 16          // splines per block
#define TROWS 128         // rows per block (8 rows/thread)
#define NTHR  256
#define KPAD  128         // global sorted-knot pitch (padded with +INF)
#define KLDS  132         // LDS pitch: 132%32==4 -> 16 cols spread 2-per-bank

// ============================================================================
// Sorted-region formulation (R8, proven): S(x) is piecewise-cubic with
// breakpoints at the sorted knot values; region index m = #{j: x >= t_j} over
// the ORIGINAL knots (order-independent count); prep sums active Q_i per
// region (fp64) -> RT[spline][m-1] float4; m=0/68 -> 0.
// R11 (proven, -12us): 7-step branchless binary search over sorted knots
// (multiset count == linear count) replaced the 68-iter scan.
// R12: kill the X-tile transpose machinery. It existed only to give waves
// wave-uniform spline columns (s_load-feed era, obsoleted by R10/R11's
// per-lane VMEM gather). Direct layout: lane = (row-slot, spline); x loaded
// straight from global (4x64B full sectors per wave-instr = ideal), y stored
// straight back. Deletes 20 of 90 LDS ops/thread + 2 barriers. Search levels
// 1-3 hoisted to 7 register pivots (one-time load, amortized over 8 rows);
// only st=8,4,2,1 hit LDS -> ~4.4 LDS ops/element (was 11.25), below the
// HBM floor. RT gather stays on the global/VMEM path (R10, proven).
// ============================================================================

__global__ __launch_bounds__(128) void prep(const float* __restrict__ T,
                                            const float* __restrict__ C,
                                            float4* __restrict__ RT,
                                            float* __restrict__ SRT) {
    __shared__ double  td[TDIM];
    __shared__ double  cd[CDIM];
    __shared__ double  R1[QI], R2[TDIM - 2], R3[TDIM - 3];
    __shared__ double4 Qd[QI];
    __shared__ float   tf[TDIM];
    __shared__ float   srt[TDIM];

    const int s = blockIdx.x;
    const int t = threadIdx.x;

    if (t < TDIM) { float v = T[s * TDIM + t]; tf[t] = v; td[t] = (double)v; }
    if (t >= 64 && t < 64 + CDIM) cd[t - 64] = (double)C[s * CDIM + t - 64];
    __syncthreads();

    // Safe reciprocals (0/0 := 0; fp64 diff is 0 iff fp32 values equal).
    if (t < TDIM - 1) { double d = td[t + 1] - td[t]; R1[t] = (d == 0.0) ? 0.0 : 1.0 / d; }
    if (t < TDIM - 2) { double d = td[t + 2] - td[t]; R2[t] = (d == 0.0) ? 0.0 : 1.0 / d; }
    if (t < TDIM - 3) { double d = td[t + 3] - td[t]; R3[t] = (d == 0.0) ? 0.0 : 1.0 / d; }
    // Rank-sort the 68 knots (ties broken by index -> deterministic).
    if (t < TDIM) {
        float v = tf[t];
        int r = 0;
        for (int k = 0; k < TDIM; ++k)
            r += (tf[k] < v) || (tf[k] == v && k < t);
        srt[r] = v;
    }
    __syncthreads();

    // Export sorted knots, padded to 128 with +INF (INF <= x always false for
    // finite x -> count unaffected).
    {
        float v = (t < TDIM) ? srt[t] : __builtin_huge_valf();
        SRT[s * KPAD + t] = v;
    }

    // Expand Q_i: cubic for interval i, sum over <=8 Cox-de Boor lattice paths.
    if (t < QI) {
        const int i = t;
        double q0 = 0, q1 = 0, q2 = 0, q3 = 0;
        for (int j = i - 3; j <= i; ++j) {
            if (j < 0 || j > CDIM - 1) continue;
            double cj = cd[j];
            for (int b2 = 0; b2 < 2; ++b2) {
                int m2 = j + b2;
                double D3 = R3[j + b2];
                double p3 = b2 ? -D3 : D3;
                double r3 = b2 ? D3 * td[j + 4] : -D3 * td[j];
                for (int b1 = 0; b1 < 2; ++b1) {
                    int m1 = m2 + b1;
                    double D2 = R2[m2 + b1];
                    double p2 = b1 ? -D2 : D2;
                    double r2 = b1 ? D2 * td[m2 + 3] : -D2 * td[m2];
                    for (int b0 = 0; b0 < 2; ++b0) {
                        if (m1 + b0 != i) continue;   // path must end at interval i
                        double D1 = R1[m1 + b0];
                        double p1 = b0 ? -D1 : D1;
                        double r1 = b0 ? D1 * td[m1 + 2] : -D1 * td[m1];
                        double a2 = p3 * p2, a1 = p3 * r2 + r3 * p2, a0 = r3 * r2;
                        q3 += cj * (a2 * p1);
                        q2 += cj * (a2 * r1 + a1 * p1);
                        q1 += cj * (a1 * r1 + a0 * p1);
                        q0 += cj * (a0 * r1);
                    }
                }
            }
        }
        double4 q; q.x = q0; q.y = q1; q.z = q2; q.w = q3;
        Qd[i] = q;
    }
    __syncthreads();

    // Region sums: for m = t in 1..67, x* = srt[m-1]; active i <=> same fp32
    // predicates as the reference. Coefficient-wise fp64 sum -> fp32 cubic.
    if (t >= 1 && t <= RTN) {
        const float xs = srt[t - 1];
        double a0 = 0, a1 = 0, a2 = 0, a3 = 0;
        for (int i = 0; i < QI; ++i) {
            if (tf[i] <= xs && xs < tf[i + 1]) {
                double4 q = Qd[i];
                a0 += q.x; a1 += q.y; a2 += q.z; a3 += q.w;
            }
        }
        float4 v; v.x = (float)a0; v.y = (float)a1; v.z = (float)a2; v.w = (float)a3;
        RT[s * RTN + (t - 1)] = v;
    }
}

__global__ __launch_bounds__(NTHR, 8) void bspline_main(const float* __restrict__ X,
                                                        const float4* __restrict__ RT,
                                                        const float* __restrict__ SRT,
                                                        float* __restrict__ O) {
    __shared__ float ks[TCOLS * KLDS];   // 8,448 B: sorted+padded knots per column

    const int tid = threadIdx.x;
    const int r0  = blockIdx.x * TROWS;
    const int s0  = blockIdx.y * TCOLS;

    // Stage sorted knots: 16 cols x 128 floats = 512 float4 pieces, 2/thread.
    // Global side coalesced (1KB/wave-instr); one-time LDS writes.
    {
        const float4* src = (const float4*)(SRT + s0 * KPAD);
        #pragma unroll
        for (int it = 0; it < 2; ++it) {
            int e = tid + it * NTHR;
            int c = e >> 5, p = e & 31;          // col, float4-piece within col
            float4 v = src[c * 32 + p];
            *(float4*)(ks + c * KLDS + p * 4) = v;
        }
    }
    __syncthreads();

    // Lane = (row-slot rs, spline col c). Wave = 4 rows x 16 cols: x loads and
    // y stores are 4 full 64B sectors per wave-instr (== ideal dense sector
    // count -> zero coalescing loss).
    const int c  = tid & 15;
    const int rs = tid >> 4;                     // 0..15
    const float* kc = ks + c * KLDS;             // bank (4c+idx)%32: 16 cols, 2/bank

    // Search levels 1-3 from registers (one-time LDS load, amortized 8 rows).
    const float pv1  = kc[63];
    const float pv2a = kc[31], pv2b = kc[95];
    const float pv3a = kc[15], pv3b = kc[47], pv3c = kc[79], pv3d = kc[111];

    const float4* rts = RT + (s0 + c) * RTN;     // per-lane base: VMEM gather path
    const float*  xp  = X + (r0 + rs) * NSPL + s0 + c;
    float*        op  = O + (r0 + rs) * NSPL + s0 + c;

    #pragma unroll
    for (int j = 0; j < 4; ++j) {                // 2 interleaved rows per iter
        const int ra = (32 * j) * NSPL, rb = (32 * j + 16) * NSPL;
        const float x0 = xp[ra];
        const float x1 = xp[rb];

        // n = #{k: srt[k] <= x} (== #{j: x >= t_j}, multiset equality, proven).
        unsigned n0 = (pv1 <= x0) ? 64u : 0u;
        unsigned n1 = (pv1 <= x1) ? 64u : 0u;
        float q0 = n0 ? pv2b : pv2a;
        float q1 = n1 ? pv2b : pv2a;
        n0 += (q0 <= x0) ? 32u : 0u;             // n ∈ {0,32,64,96}
        n1 += (q1 <= x1) ? 32u : 0u;
        float a0 = (n0 & 32u) ? pv3b : pv3a;     // kc[n+15] select tree
        float b0 = (n0 & 32u) ? pv3d : pv3c;
        float a1 = (n1 & 32u) ? pv3b : pv3a;
        float b1 = (n1 & 32u) ? pv3d : pv3c;
        float r0v = (n0 & 64u) ? b0 : a0;
        float r1v = (n1 & 64u) ? b1 : a1;
        n0 += (r0v <= x0) ? 16u : 0u;            // n ∈ {0,16,...,112}
        n1 += (r1v <= x1) ? 16u : 0u;
        #pragma unroll
        for (int st = 8; st >= 1; st >>= 1) {    // 4 LDS reads per x (max idx 119)
            float v0 = kc[n0 + st - 1];
            float v1 = kc[n1 + st - 1];
            n0 = (v0 <= x0) ? n0 + st : n0;
            n1 = (v1 <= x1) ? n1 + st : n1;
        }

        // Region m = n; table entry m-1 for m in [1,67]; m=0/68 -> 0.
        unsigned i0 = n0 - 1u; i0 = (i0 > 66u) ? 66u : i0;   // wrap(n=0)->66 too
        unsigned i1 = n1 - 1u; i1 = (i1 > 66u) ? 66u : i1;
        float4 p0 = rts[i0];                     // L1/L2-resident VMEM gather
        float4 p1 = rts[i1];
        float y0 = fmaf(fmaf(fmaf(p0.w, x0, p0.z), x0, p0.y), x0, p0.x);
        float y1 = fmaf(fmaf(fmaf(p1.w, x1, p1.z), x1, p1.y), x1, p1.x);
        y0 = (n0 - 1u < 67u) ? y0 : 0.f;         // m=0 or m=68 -> outside knots
        y1 = (n1 - 1u < 67u) ? y1 : 0.f;
        op[ra] = y0;
        op[rb] = y1;
    }
}

extern "C" void kernel_launch(void* const* d_in, const int* in_sizes, int n_in,
                              void* d_out, int out_size, void* d_ws, size_t ws_size,
                              hipStream_t stream) {
    const float* X = (const float*)d_in[0];  // [65536, 64]
    const float* T = (const float*)d_in[1];  // [64, 68]
    const float* C = (const float*)d_in[2];  // [64, 64]
    float* O = (float*)d_out;                // [65536, 64]
    float4* RT = (float4*)d_ws;              // 64*67 float4 = 68,608 B
    float* SRT = (float*)((char*)d_ws + NSPL * RTN * sizeof(float4));  // 64*128 f32 = 32 KB

    prep<<<NSPL, 128, 0, stream>>>(T, C, RT, SRT);
    dim3 grid(BATCH / TROWS, NSPL / TCOLS);  // (512, 4) = 2048 blocks, 8/CU resident
    bspline_main<<<grid, NTHR, 0, stream>>>(X, RT, SRT, O);
}